// Round 1
// baseline (109.022 us; speedup 1.0000x reference)
//
#include <hip/hip_runtime.h>

// LIF neuron, T=4, decay=0.5, vth=1.0 (soft reset).
// x: (256, 65536) f32, rows grouped as n*T+t. Each thread owns one
// (neuron n, float4-column f4) and walks t=0..3 carrying v in registers.

#define T_STEPS 4
#define DECAY   0.5f
#define VTH     1.0f

__global__ __launch_bounds__(256) void lif_kernel(
    const float4* __restrict__ x, float4* __restrict__ out, int f4_per_row) {
    int idx = blockIdx.x * blockDim.x + threadIdx.x;      // 0 .. N*F4-1
    int n   = idx / f4_per_row;                           // neuron index
    int f   = idx - n * f4_per_row;                       // float4 column

    size_t base = (size_t)n * T_STEPS * f4_per_row + f;
    const float4* xp = x + base;
    float4*       op = out + base;

    float4 v = make_float4(0.f, 0.f, 0.f, 0.f);
    #pragma unroll
    for (int t = 0; t < T_STEPS; ++t) {
        float4 xv = xp[(size_t)t * f4_per_row];
        float4 s;
        v.x = v.x * DECAY + xv.x;  s.x = (v.x >= VTH) ? 1.f : 0.f;  v.x -= s.x * VTH;
        v.y = v.y * DECAY + xv.y;  s.y = (v.y >= VTH) ? 1.f : 0.f;  v.y -= s.y * VTH;
        v.z = v.z * DECAY + xv.z;  s.z = (v.z >= VTH) ? 1.f : 0.f;  v.z -= s.z * VTH;
        v.w = v.w * DECAY + xv.w;  s.w = (v.w >= VTH) ? 1.f : 0.f;  v.w -= s.w * VTH;
        op[(size_t)t * f4_per_row] = s;
    }
}

extern "C" void kernel_launch(void* const* d_in, const int* in_sizes, int n_in,
                              void* d_out, int out_size, void* d_ws, size_t ws_size,
                              hipStream_t stream) {
    const float* x = (const float*)d_in[0];
    float* out = (float*)d_out;

    const int B = 256;                 // N*T rows
    const int F = in_sizes[0] / B;     // 65536
    const int N = B / T_STEPS;         // 64
    const int F4 = F / 4;              // 16384 float4 per row

    int total = N * F4;                // one thread per (n, f4)
    int block = 256;
    int grid  = (total + block - 1) / block;

    lif_kernel<<<grid, block, 0, stream>>>(
        (const float4*)x, (float4*)out, F4);
}